// Round 5
// baseline (308.302 us; speedup 1.0000x reference)
//
#include <hip/hip_runtime.h>
#include <hip/hip_bf16.h>
#include <math.h>

typedef __attribute__((ext_vector_type(8))) short short8;
typedef __attribute__((ext_vector_type(4))) float f32x4;
typedef unsigned short u16;

#define Sn 1024
#define En 256
#define Hn 512
#define Ln 16

__device__ inline u16 bf16b(float x) {
    union { __hip_bfloat16 h; u16 u; } cvt;
    cvt.h = __float2bfloat16(x);
    return cvt.u;
}

// ---------------- K0: fused weight-pack + embed/GELU
__global__ void prep_embed(const float* __restrict__ wA, const float* __restrict__ wB,
                           const float* __restrict__ wS, u16* __restrict__ Wt,
                           const int* __restrict__ sent, const int* __restrict__ mask,
                           const float* __restrict__ ce_w, const float* __restrict__ me_w,
                           u16* __restrict__ vemb) {
    int bx = blockIdx.x;
    if (bx < 1088) {
        int idx = bx * 256 + threadIdx.x;
        int n = idx >> 8;
        int k = idx & 255;
        float v = 0.f;
        if (n < 512)       v = wA[k * 512 + n];
        else if (n < 1024) v = wB[k * 512 + (n - 512)];
        else if (n < 1040) v = wS[k * 16 + (n - 1024)];
        Wt[idx] = bf16b(v);
    } else {
        int row = bx - 1088;
        int e = threadIdx.x;
        int s = sent[row];
        int m = mask[row];
        float ce = ce_w[s * En + e];
        float me = me_w[m * En + e];
        float g = 0.5f * me * (1.f + erff(me * 0.70710678118654752f));
        vemb[row * En + e] = bf16b(ce * g);
    }
}

// ---------------- K1: GEMM1  C(4096 x 1040) = vemb(4096x256) @ W(256x1040)
#define LDP 136   // 128 + 8 pad (shorts)
__global__ __launch_bounds__(256, 2) void gemm1(const u16* __restrict__ A, const u16* __restrict__ Bt,
                                                const float* __restrict__ bA, const float* __restrict__ bB,
                                                const float* __restrict__ bS,
                                                u16* __restrict__ va, u16* __restrict__ vb,
                                                float* __restrict__ vd,
                                                float* __restrict__ dmn, float* __restrict__ dmx) {
    __shared__ __align__(16) u16 As[64 * LDP];
    __shared__ __align__(16) u16 Bs[64 * LDP];
    int tid = threadIdx.x;
    int m0 = blockIdx.x * 64, n0 = blockIdx.y * 64;
    int lane = tid & 63, w = tid >> 6;
    int lrow = lane & 15, quad = lane >> 4;

    f32x4 acc[4];
    for (int nt = 0; nt < 4; nt++) acc[nt] = (f32x4){0.f, 0.f, 0.f, 0.f};

    for (int kb = 0; kb < 2; kb++) {            // K = 256 = 2 * 128
        for (int i = 0; i < 4; i++) {
            int off = (i * 256 + tid) * 8;
            int r = off >> 7, c = off & 127;
            *(short8*)&As[r * LDP + c] = *(const short8*)&A[(m0 + r) * 256 + kb * 128 + c];
            *(short8*)&Bs[r * LDP + c] = *(const short8*)&Bt[(n0 + r) * 256 + kb * 128 + c];
        }
        __syncthreads();
        for (int ks = 0; ks < 4; ks++) {
            short8 a = *(const short8*)&As[(w * 16 + lrow) * LDP + ks * 32 + quad * 8];
            for (int nt = 0; nt < 4; nt++) {
                short8 b = *(const short8*)&Bs[(nt * 16 + lrow) * LDP + ks * 32 + quad * 8];
                acc[nt] = __builtin_amdgcn_mfma_f32_16x16x32_bf16(a, b, acc[nt], 0, 0, 0);
            }
        }
        __syncthreads();
    }
    int mbase = m0 + w * 16 + quad * 4;
    if (blockIdx.y < 8) {
        for (int nt = 0; nt < 4; nt++) {
            int n = n0 + nt * 16 + lrow;
            float bias = bA[n];
            for (int r = 0; r < 4; r++)
                va[(mbase + r) * 512 + n] = bf16b(acc[nt][r] + bias);
        }
    } else if (blockIdx.y < 16) {
        for (int nt = 0; nt < 4; nt++) {
            int n = n0 + nt * 16 + lrow - 512;
            float bias = bB[n];
            for (int r = 0; r < 4; r++) {
                float x = acc[nt][r] + bias;
                vb[(mbase + r) * 512 + n] = bf16b(1.f / (1.f + __expf(-x)));
            }
        }
    } else {
        float bias = bS[lrow];
        for (int r = 0; r < 4; r++) {
            float x = acc[0][r] + bias;
            x = x > 0.f ? x : 0.f;
            vd[(mbase + r) * 16 + lrow] = x;
            float mn = x, mx = x;
            for (int d = 1; d < 16; d <<= 1) {
                mn = fminf(mn, __shfl_xor(mn, d));
                mx = fmaxf(mx, __shfl_xor(mx, d));
            }
            if (lrow == 0) {
                dmn[mbase + r] = mn;
                dmx[mbase + r] = mx;
            }
        }
    }
}

// ---------------- K2: fused batched GEMM2 + softmax, LDS-retiled expand phase.
// Phase 1: 64x64 vc tile via MFMA (as before), scaled, written to LDS (stride 65).
// Phase 2: thread remap -> each pass covers one i-row: j = tid>>2 (64 cols),
//          t = tid&3 (4 floats each) => every wave store is 1 KB contiguous.
__global__ __launch_bounds__(256, 2) void gemm2_softmax(const u16* __restrict__ va_g,
                                                        const u16* __restrict__ vb_g,
                                                        const float* __restrict__ vd,
                                                        const float* __restrict__ dmn,
                                                        const float* __restrict__ dmx,
                                                        float* __restrict__ out) {
    __shared__ __align__(16) u16 smem[2 * 64 * LDP];   // 34816 B; aliased below
    u16* As = smem;
    u16* Bs = smem + 64 * LDP;
    float* vcs = (float*)smem;                          // 64*65*4 = 16640 B <= 34816

    int tid = threadIdx.x;
    int b = blockIdx.z;
    int m0 = blockIdx.x * 64, n0 = blockIdx.y * 64;
    const u16* A  = va_g + (size_t)b * 1024 * 512;
    const u16* Bt = vb_g + (size_t)b * 1024 * 512;
    int lane = tid & 63, w = tid >> 6;
    int lrow = lane & 15, quad = lane >> 4;

    f32x4 acc[4];
    for (int nt = 0; nt < 4; nt++) acc[nt] = (f32x4){0.f, 0.f, 0.f, 0.f};

    for (int kb = 0; kb < 4; kb++) {            // K = 512 = 4 * 128
        for (int i = 0; i < 4; i++) {
            int off = (i * 256 + tid) * 8;
            int r = off >> 7, c = off & 127;
            *(short8*)&As[r * LDP + c] = *(const short8*)&A[(m0 + r) * 512 + kb * 128 + c];
            *(short8*)&Bs[r * LDP + c] = *(const short8*)&Bt[(n0 + r) * 512 + kb * 128 + c];
        }
        __syncthreads();
        for (int ks = 0; ks < 4; ks++) {
            short8 a = *(const short8*)&As[(w * 16 + lrow) * LDP + ks * 32 + quad * 8];
            for (int nt = 0; nt < 4; nt++) {
                short8 bfr = *(const short8*)&Bs[(nt * 16 + lrow) * LDP + ks * 32 + quad * 8];
                acc[nt] = __builtin_amdgcn_mfma_f32_16x16x32_bf16(a, bfr, acc[nt], 0, 0, 0);
            }
        }
        __syncthreads();
    }

    // Phase 1 epilogue: vc tile -> LDS (stride 65 to spread banks)
    const float invH = 1.0f / 512.0f;
    int rbase = w * 16 + quad * 4;
    for (int nt = 0; nt < 4; nt++) {
        int cl = nt * 16 + lrow;
        for (int r = 0; r < 4; r++)
            vcs[(rbase + r) * 65 + cl] = acc[nt][r] * invH;
    }
    __syncthreads();

    // Phase 2: expand + softmax with contiguous stores
    int jl = tid >> 2;           // 0..63 column within tile
    int t4 = (tid & 3) * 4;      // float offset within L=16
    int rowd = b * 1024 + n0 + jl;
    f32x4 d = *(const f32x4*)&vd[rowd * 16 + t4];
    float mn = dmn[rowd], mx = dmx[rowd];
    float* obase = out + (((size_t)(b * 1024 + m0) * 1024 + n0 + jl) * 16 + t4);
    for (int il = 0; il < 64; il++) {
        float c = vcs[il * 65 + jl];
        float mval = (c >= 0.f) ? c * mx : c * mn;
        float e0 = __expf(c * d.x - mval);
        float e1 = __expf(c * d.y - mval);
        float e2 = __expf(c * d.z - mval);
        float e3 = __expf(c * d.w - mval);
        float s = e0 + e1 + e2 + e3;
        s += __shfl_xor(s, 1);
        s += __shfl_xor(s, 2);
        float inv = 1.f / s;
        f32x4 o;
        o.x = e0 * inv; o.y = e1 * inv; o.z = e2 * inv; o.w = e3 * inv;
        __builtin_nontemporal_store(o, (f32x4*)(obase + (size_t)il * 1024 * 16));
    }
}

extern "C" void kernel_launch(void* const* d_in, const int* in_sizes, int n_in,
                              void* d_out, int out_size, void* d_ws, size_t ws_size,
                              hipStream_t stream) {
    const int*   sent = (const int*)d_in[0];
    const int*   mask = (const int*)d_in[1];
    const float* ce_w = (const float*)d_in[2];
    const float* me_w = (const float*)d_in[3];
    const float* wA   = (const float*)d_in[4];
    const float* bA   = (const float*)d_in[5];
    const float* wB   = (const float*)d_in[6];
    const float* bB   = (const float*)d_in[7];
    const float* wS   = (const float*)d_in[8];
    const float* bS   = (const float*)d_in[9];
    float* out = (float*)d_out;

    char* ws = (char*)d_ws;
    u16* vemb = (u16*)ws;  ws += (size_t)4096 * 256 * 2;
    u16* Wt   = (u16*)ws;  ws += (size_t)1088 * 256 * 2;
    u16* va   = (u16*)ws;  ws += (size_t)4096 * 512 * 2;
    u16* vb   = (u16*)ws;  ws += (size_t)4096 * 512 * 2;
    float* vd  = (float*)ws;  ws += (size_t)4096 * 16 * 4;
    float* dmn = (float*)ws;  ws += (size_t)4096 * 4;
    float* dmx = (float*)ws;  ws += (size_t)4096 * 4;

    prep_embed<<<5184, 256, 0, stream>>>(wA, wB, wS, Wt, sent, mask, ce_w, me_w, vemb);
    gemm1<<<dim3(64, 17), 256, 0, stream>>>(vemb, Wt, bA, bB, bS, va, vb, vd, dmn, dmx);
    gemm2_softmax<<<dim3(16, 16, 4), 256, 0, stream>>>(va, vb, vd, dmn, dmx, out);
}